// Round 8
// baseline (440.203 us; speedup 1.0000x reference)
//
#include <hip/hip_runtime.h>
#include <hip/hip_fp16.h>
#include <cstdint>

using f16 = _Float16;
typedef __attribute__((ext_vector_type(8))) _Float16 f16x8;
typedef __attribute__((ext_vector_type(4))) _Float16 f16x4;
typedef __attribute__((ext_vector_type(4))) float f32x4;

#define MFMA16(a, b, c) __builtin_amdgcn_mfma_f32_16x16x32_f16((a), (b), (c), 0, 0, 0)

__device__ __forceinline__ f16x8 ldfrag(const f16* p) { return *(const f16x8*)p; }

// async global->LDS DMA, 16 B per lane; lds dest = wave-uniform base + lane*16
__device__ __forceinline__ void dma16(const f16* g, f16* l) {
  __builtin_amdgcn_global_load_lds(
      (const __attribute__((address_space(1))) void*)g,
      (__attribute__((address_space(3))) void*)l, 16, 0, 0);
}
// explicit per-wave fences (do NOT rely on compiler LDS-DMA modeling)
__device__ __forceinline__ void wait_vm0() {
  asm volatile("s_waitcnt vmcnt(0)" ::: "memory");
}
__device__ __forceinline__ void wait_lgkm0() {
  asm volatile("s_waitcnt lgkmcnt(0)" ::: "memory");
}
__device__ __forceinline__ void wait_vm4() {
  asm volatile("s_waitcnt vmcnt(4)" ::: "memory");
}
__device__ __forceinline__ void wait_vm3() {
  asm volatile("s_waitcnt vmcnt(3)" ::: "memory");
}

// Problem constants: B=8, T=1024, K=128, H=8 -> M = B*H = 64 scrambled batches.
static const int64_t NX = 1048576;   // x elements: 8*1024*128
static const int64_t NW = 655360;    // Wq/Wk elements: 1024*128*5
static const int64_t NV = 131072;    // Wv / Wu elements: 1024*128

// ---------------- K0: split-convert/repack weights and x to fp16 hi/lo -----
__global__ __launch_bounds__(256) void k0_prep(
    const float* __restrict__ x, const float* __restrict__ Wq,
    const float* __restrict__ Wk, const float* __restrict__ Wv,
    const float* __restrict__ Wu,
    f16* __restrict__ xh, f16* __restrict__ xl,
    f16* __restrict__ Wqh, f16* __restrict__ Wql,
    f16* __restrict__ Wkh, f16* __restrict__ Wkl,
    f16* __restrict__ Wvb, f16* __restrict__ Wub) {
  int64_t i = (int64_t)blockIdx.x * 256 + threadIdx.x;  // grid sized exactly
  if (i < NX) {
    const float v = x[i];
    const f16 h = (f16)v;
    xh[i] = h; xl[i] = (f16)(v - (float)h);
  } else if (i < NX + NW) {
    int64_t d = i - NX;
    int j = (int)(d >> 17);
    int rem = (int)(d & 131071);
    int o = rem >> 7, c = rem & 127;
    const float v = Wq[(int64_t)(o * 128 + c) * 5 + j];   // layout [j][o][c]
    const f16 h = (f16)v;
    Wqh[d] = h; Wql[d] = (f16)(v - (float)h);
  } else if (i < NX + 2 * NW) {
    int64_t d = i - NX - NW;
    int j = (int)(d >> 17);
    int rem = (int)(d & 131071);
    int o = rem >> 7, c = rem & 127;
    const float v = Wk[(int64_t)(o * 128 + c) * 5 + j];
    const f16 h = (f16)v;
    Wkh[d] = h; Wkl[d] = (f16)(v - (float)h);
  } else if (i < NX + 2 * NW + NV) {
    int64_t d = i - NX - 2 * NW;
    Wvb[d] = (f16)Wv[d];                                // [o][c]
  } else {
    int64_t d = i - NX - 2 * NW - NV;
    Wub[d] = (f16)Wu[d];                                // [c][o]
  }
}

// ---------------- K1: causal convs, 64 T-rows/block ------------------------
// 64 rows doubles MFMA per streamed weight byte (48 MFMA per 2 KB chunk) and
// halves total weight re-streaming. Staging runs in two 256-row passes.
// Wave-private wbuf slots; per-wave vmcnt/lgkmcnt fences; barriers only
// around cross-wave staging.
#define STAGE_QK(DST, PASS, VALEXPR)                                    \
  {                                                                     \
    __syncthreads();                                                    \
    _Pragma("unroll")                                                   \
    for (int nt = 0; nt < 8; ++nt) {                                    \
      const int o = o0 + nt * 16 + lo;                                  \
      const int kcl = (o >> 3) & 63, hh = o & 7;                        \
      _Pragma("unroll")                                                 \
      for (int rtl = 0; rtl < 2; ++rtl) {                               \
        const int rt = (PASS) * 2 + rtl;                                \
        _Pragma("unroll")                                               \
        for (int r = 0; r < 4; ++r) {                                   \
          const int t2l = (rtl * 16 + quad * 4 + r) * 8 + hh;           \
          lds[t2l * 72 + kcl] = (VALEXPR);                              \
        }                                                               \
      }                                                                 \
    }                                                                   \
    __syncthreads();                                                    \
    _Pragma("unroll")                                                   \
    for (int p = 0; p < 8; ++p) {                                       \
      const int idx = p * 256 + tid;                                    \
      const int a = idx >> 3, c8 = (idx & 7) * 8;                       \
      *(f16x8*)(DST + ((int64_t)m * 1024 + t2b + (PASS) * 256 + a) * 128 + \
                half * 64 + c8) = *(const f16x8*)&lds[a * 72 + c8];     \
    }                                                                   \
  }

__global__ __launch_bounds__(256) void k1_conv(
    const f16* __restrict__ xh, const f16* __restrict__ xl,
    const f16* __restrict__ Wqh, const f16* __restrict__ Wql,
    const f16* __restrict__ Wkh, const f16* __restrict__ Wkl,
    const f16* __restrict__ Wvb,
    const float* __restrict__ bq, const float* __restrict__ bk,
    const float* __restrict__ bv,
    f16* __restrict__ q3h, f16* __restrict__ q3l,
    f16* __restrict__ k3h, f16* __restrict__ k3l,
    f16* __restrict__ v3T) {
  __shared__ f16 shm[36384];      // 72.8 KB: [0,18432) wbuf/stage, rest xbuf
  f16* const wbuf = shm;
  f16* const xbuf = shm + 18432;  // 68 rows x 264 f16
  f16* const lds  = shm;          // staging alias
  const int tid = threadIdx.x;
  const int w = tid >> 6, lane = tid & 63;
  const int quad = lane >> 4, lo = lane & 15;
  const int r0 = blockIdx.x * 64;     // rows r0..r0+63 (same b, same m)
  const int bb = r0 >> 10;
  const int m  = r0 >> 7;
  const int t2b = (r0 & 127) * 8;     // 0 or 512
  const int tloc = r0 & 1023;
  const int half = blockIdx.y;        // which 512-channel half
  const int isK = blockIdx.z;         // 0 = Q (+V), 1 = K
  const int o0 = half * 512 + w * 128;

  const f16* Wh = isK ? Wkh : Wqh;
  const f16* Wl = isK ? Wkl : Wql;
  const float* bias = isK ? bk : bq;

  // ---- stage x rows [tloc-4, tloc+64) (clamped at batch start) ----
#pragma unroll
  for (int p = 0; p < 9; ++p) {
    const int u = p * 256 + tid;           // f16x8 unit
    if (u < 2176) {
      const int row = u >> 5, tz = (u >> 4) & 1, c8 = (u & 15) * 8;
      int lt = tloc - 4 + row;
      if (lt < 0) lt = 0;
      const f16* src = (tz ? xl : xh) + ((int64_t)(bb * 1024 + lt)) * 128 + c8;
      *(f16x8*)&xbuf[row * 264 + tz * 128 + c8] = *(const f16x8*)src;
    }
  }
  __syncthreads();

  // per-lane gather offset within a 16n x 128c fragment block
  const int64_t wlane = (int64_t)(lane & 15) * 128 + (lane >> 4) * 8;

  // ---- V pass (Q-blocks only): pointwise tap, hi only; barrier-free ----
  if (!isK) {
    f32x4 av[4][8];
#pragma unroll
    for (int rt = 0; rt < 4; ++rt)
#pragma unroll
      for (int i = 0; i < 8; ++i)
#pragma unroll
        for (int r = 0; r < 4; ++r) av[rt][i][r] = 0.f;

#pragma unroll
    for (int g = 0; g < 4; ++g) {
#pragma unroll
      for (int s = 0; s < 2; ++s) {
        const int64_t vsrc = (int64_t)(o0 + (g * 2 + s) * 16) * 128 + wlane;
#pragma unroll
        for (int kk = 0; kk < 4; ++kk)
          dma16(Wvb + vsrc + kk * 32, wbuf + w * 4096 + s * 2048 + kk * 512);
      }
      wait_vm0();   // own DMA landed
#pragma unroll
      for (int kk = 0; kk < 4; ++kk) {
        f16x8 a[4];
#pragma unroll
        for (int rt = 0; rt < 4; ++rt)
          a[rt] = *(const f16x8*)&xbuf[(rt * 16 + lo + 4) * 264 + kk * 32 +
                                       quad * 8];
#pragma unroll
        for (int s = 0; s < 2; ++s) {
          const f16x8 bv8 = *(const f16x8*)&wbuf[w * 4096 + s * 2048 + kk * 512 +
                                                 quad * 128 + lo * 8];
#pragma unroll
          for (int rt = 0; rt < 4; ++rt)
            av[rt][g * 2 + s] = MFMA16(a[rt], bv8, av[rt][g * 2 + s]);
        }
      }
      wait_lgkm0();  // own ds_reads sampled before next DMA can land
    }
    __syncthreads();  // all waves done with wbuf before cross-wave staging
    // bias + stage v3T via LDS [kcl][t2l] (stride 264), two 256-col passes
#pragma unroll
    for (int pass = 0; pass < 2; ++pass) {
#pragma unroll
      for (int nt = 0; nt < 8; ++nt) {
        const int o = o0 + nt * 16 + lo;
        const float vbv = bv[o];
        const int kcl = (o >> 3) & 63, hh = o & 7;
#pragma unroll
        for (int rtl = 0; rtl < 2; ++rtl)
#pragma unroll
          for (int r = 0; r < 4; ++r) {
            const int t2l = (rtl * 16 + quad * 4 + r) * 8 + hh;
            lds[kcl * 264 + t2l] = (f16)(av[pass * 2 + rtl][nt][r] + vbv);
          }
      }
      __syncthreads();
#pragma unroll
      for (int p = 0; p < 8; ++p) {
        const int idx = p * 256 + tid;
        const int kcl = idx >> 5, t8 = (idx & 31) * 8;
        *(f16x8*)(v3T + ((int64_t)m * 128 + half * 64 + kcl) * 1024 + t2b +
                  pass * 256 + t8) = *(const f16x8*)&lds[kcl * 264 + t8];
      }
      __syncthreads();  // staging reads done before next pass / wbuf reuse
    }
  }

  // ---- Q or K main: 5 taps x 8 nt chunks, barrier-free stream ----
  f32x4 aq[4][8];
#pragma unroll
  for (int rt = 0; rt < 4; ++rt)
#pragma unroll
    for (int i = 0; i < 8; ++i)
#pragma unroll
      for (int r = 0; r < 4; ++r) { aq[rt][i][r] = 0.f; }

  for (int j = 0; j < 5; ++j) {
    const bool z0 = (tloc == 0);
#pragma unroll
    for (int nt = 0; nt < 8; ++nt) {
      const int64_t wsrc =
          (int64_t)j * 131072 + (int64_t)(o0 + nt * 16) * 128 + wlane;
#pragma unroll
      for (int kk = 0; kk < 4; ++kk) {
        dma16(Wh + wsrc + kk * 32, wbuf + w * 4096 + kk * 512);
        dma16(Wl + wsrc + kk * 32, wbuf + w * 4096 + 2048 + kk * 512);
      }
      wait_vm4();   // kk0/kk1 (h+l) landed; kk2/kk3 still in flight
#pragma unroll
      for (int kk = 0; kk < 4; ++kk) {
        if (kk == 2) wait_vm0();   // kk2/kk3 landed
        const f16x8 bh =
            *(const f16x8*)&wbuf[w * 4096 + kk * 512 + quad * 128 + lo * 8];
        const f16x8 bl =
            *(const f16x8*)&wbuf[w * 4096 + 2048 + kk * 512 + quad * 128 + lo * 8];
#pragma unroll
        for (int rt = 0; rt < 4; ++rt) {
          f16x8 ah = *(const f16x8*)&xbuf[(rt * 16 + lo + j) * 264 + kk * 32 +
                                          quad * 8];
          f16x8 al = *(const f16x8*)&xbuf[(rt * 16 + lo + j) * 264 + 128 +
                                          kk * 32 + quad * 8];
          if (rt == 0 && z0 && (lo + j < 4)) {
#pragma unroll
            for (int e = 0; e < 8; ++e) { ah[e] = (f16)0; al[e] = (f16)0; }
          }
          aq[rt][nt] = MFMA16(ah, bh, aq[rt][nt]);
          aq[rt][nt] = MFMA16(ah, bl, aq[rt][nt]);
          aq[rt][nt] = MFMA16(al, bh, aq[rt][nt]);
        }
      }
      wait_lgkm0();  // ds_reads sampled before next chunk's DMA lands
    }
  }

  const float SC = 0.29730177875068026f;  // 128^-0.25
#pragma unroll
  for (int nt = 0; nt < 8; ++nt) {
    const int o = o0 + nt * 16 + lo;
    const float vb = bias[o];
#pragma unroll
    for (int rt = 0; rt < 4; ++rt)
#pragma unroll
      for (int r = 0; r < 4; ++r) aq[rt][nt][r] = (aq[rt][nt][r] + vb) * SC;
  }

  if (!isK) {
    STAGE_QK(q3h, 0, (f16)aq[rt][nt][r])
    STAGE_QK(q3h, 1, (f16)aq[rt][nt][r])
    STAGE_QK(q3l, 0, (f16)(aq[rt][nt][r] - (float)(f16)aq[rt][nt][r]))
    STAGE_QK(q3l, 1, (f16)(aq[rt][nt][r] - (float)(f16)aq[rt][nt][r]))
  } else {
    STAGE_QK(k3h, 0, (f16)aq[rt][nt][r])
    STAGE_QK(k3h, 1, (f16)aq[rt][nt][r])
    STAGE_QK(k3l, 0, (f16)(aq[rt][nt][r] - (float)(f16)aq[rt][nt][r]))
    STAGE_QK(k3l, 1, (f16)(aq[rt][nt][r] - (float)(f16)aq[rt][nt][r]))
  }
}

// ---------------- K234: piece-pipelined scores + top-64/softmax + PV -------
// 4-deep counted-vmcnt piece ring (T4): each wave streams 1KB pieces through
// its 4 kbuf slots; EVERY wait is vmcnt(3) (never drain to 0 mid-stream).
// The ring runs continuously: 64 K pieces (both halves, flying across the
// S-write/snapshot barriers) then V pieces (warm-up issued during the last
// 4 K steps, so V latency hides under the radix). Bank-swizzle from R7
// preserved (coalesced 64B segments + conflict-free ds_read_b128).
// Radix early-exit; XCD m-swizzle; causal-truncated PV.
__global__ __launch_bounds__(512, 4) void k234_attn(
    const f16* __restrict__ q3h, const f16* __restrict__ q3l,
    const f16* __restrict__ k3h, const f16* __restrict__ k3l,
    const f16* __restrict__ v3T, f16* __restrict__ A) {
  __shared__ float Sb[16 * 516];   // 33,024 B: S fp32 half / P f16 full
  __shared__ f16 kbuf[16384];      // 32,768 B: 8 waves x 4 slots x 512 f16
  const int tid = threadIdx.x;
  const int w = tid >> 6, lane = tid & 63;
  const int quad = lane >> 4, lo = lane & 15;
  const int qd = lane & 3, cit = lane >> 2;       // DMA lanes: [row][piece]
  const int qsw = qd ^ ((cit >> 1) & 3);          // bank-swizzled piece
  const int fro = (lo * 4 + (quad ^ ((lo >> 1) & 3))) * 8;  // fragment read
  // bijective XCD-locality remap of (m, r0): 4096 blocks = 8 xcd * 8 m * 64 r0
  const int hid = blockIdx.y * 64 + blockIdx.x;  // hardware linear id
  const int m = (hid & 7) * 8 + ((hid >> 3) >> 6);
  const int r0 = ((hid >> 3) & 63) * 16;

  // Q fragments (A-operand) for rows r0..r0+15, all K
  const int64_t qoff = ((int64_t)m * 1024 + r0 + lo) * 128;
  f16x8 qh[4], ql[4];
#pragma unroll
  for (int kk = 0; kk < 4; ++kk) {
    qh[kk] = ldfrag(q3h + qoff + kk * 32 + quad * 8);
    ql[kk] = ldfrag(q3l + qoff + kk * 32 + quad * 8);
  }

  // piece-ring bases
  const int64_t kfb = ((int64_t)m * 1024 + w * 16 + cit) * 128 + qsw * 8;
  const f16* const khp = k3h + kfb;
  const f16* const klp = k3l + kfb;
  f16* const wslot = kbuf + w * 2048;            // 4 slots x 512 f16
  const int64_t vrow = (int64_t)(m * 128 + w * 16 + cit) * 1024 + qsw * 8;
  const int nkb = (r0 >> 6) + 1;                 // causal: P==0 beyond r0+15
  const int NV2 = nkb * 2;

  // K piece p (0..63): half=p>>5, kp=(p>>4)&1, cc=(p>>2)&3, kkh=(p>>1)&1,
  // t=p&1 (0=hi,1=lo). addr = rows(half*512+cc*128) + kcols (kp*2+kkh)*32.
#define KOFF(p)                                                          \
  ((int64_t)(((p) >> 5) * 512 + (((p) >> 2) & 3) * 128) * 128 +          \
   ((((p) >> 4) & 1) * 2 + (((p) >> 1) & 1)) * 32)
#define KISSUE(p)                                                        \
  dma16(((p)&1 ? klp : khp) + KOFF(p), wslot + ((p)&3) * 512);
  // V piece v: kb=v>>1 (clamped -> dummy re-reads hot lines), 32-col half v&1
#define VISSUE(v)                                                        \
  dma16(v3T + vrow + (int64_t)((((v) >> 1) < nkb ? ((v) >> 1) : 0)) * 64 + \
            ((v)&1) * 32,                                                \
        wslot + ((v)&3) * 512);

  // prologue: fill the ring (Q ldfrags are older in the vmcnt FIFO, so
  // vmcnt(3) also guarantees Q landed at the first consume)
  KISSUE(0) KISSUE(1) KISSUE(2) KISSUE(3)

  unsigned key[2][16];
  unsigned kmn0 = 0xFFFFFFFFu, kmn1 = 0xFFFFFFFFu;

  // ---- phase 1: S = Q @ K^T, 4-deep piece stream --------------------------
#pragma unroll
  for (int half = 0; half < 2; ++half) {
    f32x4 acc[4];
#pragma unroll
    for (int i = 0; i < 4; ++i)
#pragma unroll
      for (int r = 0; r < 4; ++r) acc[i][r] = 0.f;

#pragma unroll
    for (int ph = 0; ph < 32; ++ph) {
      const int p = half * 32 + ph;
      wait_vm3();                       // piece p landed; 3 stay in flight
      const f16x8 x = *(const f16x8*)(wslot + (p & 3) * 512 + fro);
      const int kkg = ((p >> 4) & 1) * 2 + ((p >> 1) & 1);
      const int cc = (p >> 2) & 3;
      if ((p & 1) == 0) {               // bh piece: 2 MFMA
        acc[cc] = MFMA16(qh[kkg], x, acc[cc]);
        acc[cc] = MFMA16(ql[kkg], x, acc[cc]);
      } else {                          // bl piece: 1 MFMA
        acc[cc] = MFMA16(qh[kkg], x, acc[cc]);
      }
      wait_lgkm0();                     // slot read sampled before re-target
      if (p + 4 < 64) { KISSUE(p + 4) } // continue K stream
      else { VISSUE(p + 4 - 64) }       // V warm-up rides over the radix
    }

    // write S half (cols half*512 .. +511)
#pragma unroll
    for (int cc = 0; cc < 4; ++cc)
#pragma unroll
      for (int r = 0; r < 4; ++r)
        Sb[(quad * 4 + r) * 516 + cc * 128 + w * 16 + lo] = acc[cc][r];
    __syncthreads();   // cross-wave: snapshot reads other waves' columns
    // snapshot keys: wave w owns rows 2w, 2w+1 (in-flight DMAs are
    // wave-private kbuf slots, disjoint from Sb -> safe across barriers)
#pragma unroll
    for (int rr = 0; rr < 2; ++rr) {
      const float4* rp = (const float4*)(Sb + (w * 2 + rr) * 516);
#pragma unroll
      for (int i2 = 0; i2 < 2; ++i2) {
        const float4 f4 = rp[i2 * 64 + lane];
        const float fe[4] = {f4.x, f4.y, f4.z, f4.w};
#pragma unroll
        for (int e = 0; e < 4; ++e) {
          const unsigned u = __builtin_bit_cast(unsigned, fe[e]);
          const unsigned k = (u & 0x80000000u) ? ~u : (u | 0x80000000u);
          key[rr][half * 8 + i2 * 4 + e] = k;
          if (rr == 0) kmn0 = min(kmn0, k); else kmn1 = min(kmn1, k);
        }
      }
    }
    __syncthreads();  // all key reads done before next half overwrites S
  }

  // ---- phase 2: exact fp32 top-64 + rowmin + causal + softmax -> P --------
  // (V pieces 0..3 in flight, landing under this VALU phase)
  f16* P16 = (f16*)Sb;  // row stride 1032 f16 (= 516 f32)
  {
#pragma unroll
    for (int off = 32; off; off >>= 1) {
      kmn0 = min(kmn0, (unsigned)__shfl_xor((int)kmn0, off));
      kmn1 = min(kmn1, (unsigned)__shfl_xor((int)kmn1, off));
    }
    // radix-select with exact-count early exit: when count(>=c)==64 the
    // selected set {k>=c} IS the top-64 (identical to the full scan's set).
    unsigned th0 = 0u, th1 = 0u;
    bool d0 = false, d1 = false;
    for (int b = 31; b >= 0; --b) {
      if (!d0) {
        const unsigned c0 = th0 | (1u << b);
        int cnt0 = 0;
#pragma unroll
        for (int i = 0; i < 16; ++i)
          cnt0 += (int)__popcll(__ballot(key[0][i] >= c0));
        if (cnt0 >= 64) { th0 = c0; if (cnt0 == 64) d0 = true; }
      }
      if (!d1) {
        const unsigned c1 = th1 | (1u << b);
        int cnt1 = 0;
#pragma unroll
        for (int i = 0; i < 16; ++i)
          cnt1 += (int)__popcll(__ballot(key[1][i] >= c1));
        if (cnt1 >= 64) { th1 = c1; if (cnt1 == 64) d1 = true; }
      }
      if (d0 && d1) break;
    }

#pragma unroll
    for (int rr = 0; rr < 2; ++rr) {
      const unsigned kth = rr ? th1 : th0;
      const unsigned kmn = rr ? kmn1 : kmn0;
      const int row = w * 2 + rr, t2 = r0 + row;
      const unsigned umn = (kmn & 0x80000000u) ? (kmn ^ 0x80000000u) : ~kmn;
      const float mn = __builtin_bit_cast(float, umn);   // exact row min
      const unsigned ukv = (kth & 0x80000000u) ? (kth ^ 0x80000000u) : ~kth;
      const float kv = __builtin_bit_cast(float, ukv);   // selection threshold

      float ev[16];
      float sum = 0.f;
#pragma unroll
      for (int j = 0; j < 16; ++j) {
        const int s = (j >> 3) * 512 + ((j >> 2) & 1) * 256 + lane * 4 + (j & 3);
        const unsigned k = key[rr][j];
        const unsigned uu = (k & 0x80000000u) ? (k ^ 0x80000000u) : ~k;
        const float f = __builtin_bit_cast(float, uu);
        const float ww = (k >= kth) ? f : mn;
        const float x = (s <= t2) ? __expf(ww - kv) : 0.f;  // kv-stabilized
        ev[j] = x;
        sum += x;
      }
      for (int off = 32; off; off >>= 1) sum += __shfl_xor(sum, off);
      const float inv = 1.0f / sum;

      f16* prow = P16 + row * 1032;  // in place over this row's S
#pragma unroll
      for (int hh = 0; hh < 2; ++hh)
#pragma unroll
        for (int i2 = 0; i2 < 2; ++i2) {
          f16x4 pk;
#pragma unroll
          for (int e = 0; e < 4; ++e)
            pk[e] = (f16)(ev[hh * 8 + i2 * 4 + e] * inv);
          *(f16x4*)(prow + hh * 512 + i2 * 256 + lane * 4) = pk;
        }
    }
  }
  __syncthreads();  // P visible to all waves

  // ---- phase 3: A = P @ V, same 4-deep ring; every wait vmcnt(3) ---------
  {
    f32x4 oa0, oa1;
#pragma unroll
    for (int r = 0; r < 4; ++r) { oa0[r] = 0.f; oa1[r] = 0.f; }
    for (int v = 0; v < NV2; ++v) {
      wait_vm3();                        // V piece v landed
      const f16x8 vf = *(const f16x8*)(wslot + (v & 3) * 512 + fro);
      const f16x8 af = *(const f16x8*)(P16 + lo * 1032 + v * 32 + quad * 8);
      if (v & 1) oa1 = MFMA16(af, vf, oa1);
      else       oa0 = MFMA16(af, vf, oa0);
      wait_lgkm0();                      // reads sampled before slot reuse
      VISSUE(v + 4)                      // clamped dummy past NV2 keeps
    }                                    // the wait count uniform
    wait_vm0();                          // drain leftovers before exit
#undef VISSUE
#undef KISSUE
#undef KOFF
#pragma unroll
    for (int r = 0; r < 4; ++r)
      A[((int64_t)m * 1024 + r0 + quad * 4 + r) * 128 + w * 16 + lo] =
          (f16)(oa0[r] + oa1[r]);
  }
}

// ---------------- K5: gather + output projection + bias --------------------
__global__ __launch_bounds__(256) void k5_proj(
    const f16* __restrict__ A, const f16* __restrict__ Wub,
    const float* __restrict__ bu, float* __restrict__ out) {
  const int w = threadIdx.x >> 6, lane = threadIdx.x & 63;
  const int quad = lane >> 4, lo = lane & 15;
  const int rt = w & 1, ch = w >> 1;
  const int r0 = blockIdx.x * 32 + rt * 16;  // row in [0,8192) = b*1024 + t2
  const int r = r0 + lo;
  const int bI = r >> 10, t2 = r & 1023;

  f32x4 acc[4];
#pragma unroll
  for (int i = 0; i < 4; ++i)
#pragma unroll
    for (int rr = 0; rr < 4; ++rr) acc[i][rr] = 0.f;

#pragma unroll 2
  for (int kk = 0; kk < 32; ++kk) {
    const int o = kk * 32 + quad * 8;  // feature index 0..1023
    const int j = o >> 7, kc = o & 127;
    f16x8 a = ldfrag(A + (((int64_t)(bI * 8 + j) * 1024 + t2) * 128 + kc));
    f16x8 wb[4];
#pragma unroll
    for (int nt = 0; nt < 4; ++nt)
      wb[nt] = ldfrag(Wub + (int64_t)(ch * 64 + nt * 16 + lo) * 1024 + o);
#pragma unroll
    for (int nt = 0; nt < 4; ++nt) acc[nt] = MFMA16(a, wb[nt], acc[nt]);
  }
#pragma unroll
  for (int nt = 0; nt < 4; ++nt) {
    const int col = ch * 64 + nt * 16 + lo;
    const float bias = bu[col];
#pragma unroll
    for (int rr = 0; rr < 4; ++rr) {
      const int row = r0 + quad * 4 + rr;
      out[(int64_t)row * 128 + col] = acc[nt][rr] + bias;
    }
  }
}

// ---------------- launcher --------------------------------------------------
extern "C" void kernel_launch(void* const* d_in, const int* in_sizes, int n_in,
                              void* d_out, int out_size, void* d_ws, size_t ws_size,
                              hipStream_t stream) {
  const float* x  = (const float*)d_in[0];
  const float* Wq = (const float*)d_in[1];
  const float* bq = (const float*)d_in[2];
  const float* Wk = (const float*)d_in[3];
  const float* bk = (const float*)d_in[4];
  const float* Wv = (const float*)d_in[5];
  const float* bv = (const float*)d_in[6];
  const float* Wu = (const float*)d_in[7];
  const float* bu = (const float*)d_in[8];
  float* out = (float*)d_out;

  char* ws = (char*)d_ws;
  f16* xh  = (f16*)ws;  ws += 2097152;
  f16* xl  = (f16*)ws;  ws += 2097152;
  f16* Wqh = (f16*)ws;  ws += 1310720;
  f16* Wql = (f16*)ws;  ws += 1310720;
  f16* Wkh = (f16*)ws;  ws += 1310720;
  f16* Wkl = (f16*)ws;  ws += 1310720;
  f16* Wvb = (f16*)ws;  ws += 262144;
  f16* Wub = (f16*)ws;  ws += 262144;
  f16* q3h = (f16*)ws;  ws += 16777216;           // 64*1024*128 fp16
  f16* q3l = (f16*)ws;  ws += 16777216;
  f16* k3h = (f16*)ws;  ws += 16777216;
  f16* k3l = (f16*)ws;  ws += 16777216;
  f16* v3T = (f16*)ws;  ws += 16777216;
  f16* A   = (f16*)ws;  ws += 16777216;           // total ~105.5 MB

  // K0: repack (exactly 2621440 threads = 10240 * 256)
  k0_prep<<<10240, 256, 0, stream>>>(x, Wq, Wk, Wv, Wu,
                                     xh, xl, Wqh, Wql, Wkh, Wkl, Wvb, Wub);

  // K1: convs + scramble; 64 T-rows/block, DMA-streamed weights
  k1_conv<<<dim3(128, 2, 2), 256, 0, stream>>>(xh, xl, Wqh, Wql, Wkh, Wkl, Wvb,
                                               bq, bk, bv, q3h, q3l, k3h, k3l,
                                               v3T);

  // K234: 4-deep counted-vmcnt piece pipeline, swizzled, XCD-remapped
  k234_attn<<<dim3(64, 64), 512, 0, stream>>>(q3h, q3l, k3h, k3l, v3T, A);

  // K5: projection (8192 rows / 32 per block)
  k5_proj<<<256, 256, 0, stream>>>(A, Wub, bu, out);

  (void)in_sizes; (void)n_in; (void)out_size; (void)ws_size;
}

// Round 9
// 411.731 us; speedup vs baseline: 1.0692x; 1.0692x over previous
//
#include <hip/hip_runtime.h>
#include <hip/hip_fp16.h>
#include <cstdint>

using f16 = _Float16;
typedef __attribute__((ext_vector_type(8))) _Float16 f16x8;
typedef __attribute__((ext_vector_type(4))) _Float16 f16x4;
typedef __attribute__((ext_vector_type(4))) float f32x4;

#define MFMA16(a, b, c) __builtin_amdgcn_mfma_f32_16x16x32_f16((a), (b), (c), 0, 0, 0)

__device__ __forceinline__ f16x8 ldfrag(const f16* p) { return *(const f16x8*)p; }

// async global->LDS DMA, 16 B per lane; lds dest = wave-uniform base + lane*16
__device__ __forceinline__ void dma16(const f16* g, f16* l) {
  __builtin_amdgcn_global_load_lds(
      (const __attribute__((address_space(1))) void*)g,
      (__attribute__((address_space(3))) void*)l, 16, 0, 0);
}
// explicit per-wave fences (do NOT rely on compiler LDS-DMA modeling)
__device__ __forceinline__ void wait_vm0() {
  asm volatile("s_waitcnt vmcnt(0)" ::: "memory");
}
__device__ __forceinline__ void wait_lgkm0() {
  asm volatile("s_waitcnt lgkmcnt(0)" ::: "memory");
}
__device__ __forceinline__ void wait_vm4() {
  asm volatile("s_waitcnt vmcnt(4)" ::: "memory");
}
__device__ __forceinline__ void wait_vm2() {
  asm volatile("s_waitcnt vmcnt(2)" ::: "memory");
}

// Problem constants: B=8, T=1024, K=128, H=8 -> M = B*H = 64 scrambled batches.
static const int64_t NX = 1048576;   // x elements: 8*1024*128
static const int64_t NW = 655360;    // Wq/Wk elements: 1024*128*5
static const int64_t NV = 131072;    // Wv / Wu elements: 1024*128

// ---------------- K0: split-convert/repack weights and x to fp16 hi/lo -----
__global__ __launch_bounds__(256) void k0_prep(
    const float* __restrict__ x, const float* __restrict__ Wq,
    const float* __restrict__ Wk, const float* __restrict__ Wv,
    const float* __restrict__ Wu,
    f16* __restrict__ xh, f16* __restrict__ xl,
    f16* __restrict__ Wqh, f16* __restrict__ Wql,
    f16* __restrict__ Wkh, f16* __restrict__ Wkl,
    f16* __restrict__ Wvb, f16* __restrict__ Wub) {
  int64_t i = (int64_t)blockIdx.x * 256 + threadIdx.x;  // grid sized exactly
  if (i < NX) {
    const float v = x[i];
    const f16 h = (f16)v;
    xh[i] = h; xl[i] = (f16)(v - (float)h);
  } else if (i < NX + NW) {
    int64_t d = i - NX;
    int j = (int)(d >> 17);
    int rem = (int)(d & 131071);
    int o = rem >> 7, c = rem & 127;
    const float v = Wq[(int64_t)(o * 128 + c) * 5 + j];   // layout [j][o][c]
    const f16 h = (f16)v;
    Wqh[d] = h; Wql[d] = (f16)(v - (float)h);
  } else if (i < NX + 2 * NW) {
    int64_t d = i - NX - NW;
    int j = (int)(d >> 17);
    int rem = (int)(d & 131071);
    int o = rem >> 7, c = rem & 127;
    const float v = Wk[(int64_t)(o * 128 + c) * 5 + j];
    const f16 h = (f16)v;
    Wkh[d] = h; Wkl[d] = (f16)(v - (float)h);
  } else if (i < NX + 2 * NW + NV) {
    int64_t d = i - NX - 2 * NW;
    Wvb[d] = (f16)Wv[d];                                // [o][c]
  } else {
    int64_t d = i - NX - 2 * NW - NV;
    Wub[d] = (f16)Wu[d];                                // [c][o]
  }
}

// ---------------- K1: causal convs, 64 T-rows/block ------------------------
// Loop order (j, kk) outer so the 8 A-fragments (which do NOT depend on nt)
// are loaded ONCE per (j,kk): A ds_reads drop 1280 -> 160 per wave (k1 was
// LDS-issue-bound). DMA/wait structure per 8-piece chunk unchanged (vm4/vm0).
#define STAGE_QK(DST, PASS, VALEXPR)                                    \
  {                                                                     \
    __syncthreads();                                                    \
    _Pragma("unroll")                                                   \
    for (int nt = 0; nt < 8; ++nt) {                                    \
      const int o = o0 + nt * 16 + lo;                                  \
      const int kcl = (o >> 3) & 63, hh = o & 7;                        \
      _Pragma("unroll")                                                 \
      for (int rtl = 0; rtl < 2; ++rtl) {                               \
        const int rt = (PASS) * 2 + rtl;                                \
        _Pragma("unroll")                                               \
        for (int r = 0; r < 4; ++r) {                                   \
          const int t2l = (rtl * 16 + quad * 4 + r) * 8 + hh;           \
          lds[t2l * 72 + kcl] = (VALEXPR);                              \
        }                                                               \
      }                                                                 \
    }                                                                   \
    __syncthreads();                                                    \
    _Pragma("unroll")                                                   \
    for (int p = 0; p < 8; ++p) {                                       \
      const int idx = p * 256 + tid;                                    \
      const int a = idx >> 3, c8 = (idx & 7) * 8;                       \
      *(f16x8*)(DST + ((int64_t)m * 1024 + t2b + (PASS) * 256 + a) * 128 + \
                half * 64 + c8) = *(const f16x8*)&lds[a * 72 + c8];     \
    }                                                                   \
  }

__global__ __launch_bounds__(256) void k1_conv(
    const f16* __restrict__ xh, const f16* __restrict__ xl,
    const f16* __restrict__ Wqh, const f16* __restrict__ Wql,
    const f16* __restrict__ Wkh, const f16* __restrict__ Wkl,
    const f16* __restrict__ Wvb,
    const float* __restrict__ bq, const float* __restrict__ bk,
    const float* __restrict__ bv,
    f16* __restrict__ q3h, f16* __restrict__ q3l,
    f16* __restrict__ k3h, f16* __restrict__ k3l,
    f16* __restrict__ v3T) {
  __shared__ f16 shm[36384];      // 72.8 KB: [0,18432) wbuf/stage, rest xbuf
  f16* const wbuf = shm;
  f16* const xbuf = shm + 18432;  // 68 rows x 264 f16
  f16* const lds  = shm;          // staging alias
  const int tid = threadIdx.x;
  const int w = tid >> 6, lane = tid & 63;
  const int quad = lane >> 4, lo = lane & 15;
  const int r0 = blockIdx.x * 64;     // rows r0..r0+63 (same b, same m)
  const int bb = r0 >> 10;
  const int m  = r0 >> 7;
  const int t2b = (r0 & 127) * 8;     // 0 or 512
  const int tloc = r0 & 1023;
  const int half = blockIdx.y;        // which 512-channel half
  const int isK = blockIdx.z;         // 0 = Q (+V), 1 = K
  const int o0 = half * 512 + w * 128;

  const f16* Wh = isK ? Wkh : Wqh;
  const f16* Wl = isK ? Wkl : Wql;
  const float* bias = isK ? bk : bq;

  // ---- stage x rows [tloc-4, tloc+64) (clamped at batch start) ----
#pragma unroll
  for (int p = 0; p < 9; ++p) {
    const int u = p * 256 + tid;           // f16x8 unit
    if (u < 2176) {
      const int row = u >> 5, tz = (u >> 4) & 1, c8 = (u & 15) * 8;
      int lt = tloc - 4 + row;
      if (lt < 0) lt = 0;
      const f16* src = (tz ? xl : xh) + ((int64_t)(bb * 1024 + lt)) * 128 + c8;
      *(f16x8*)&xbuf[row * 264 + tz * 128 + c8] = *(const f16x8*)src;
    }
  }
  __syncthreads();

  // per-lane gather offset within a 16n x 128c fragment block
  const int64_t wlane = (int64_t)(lane & 15) * 128 + (lane >> 4) * 8;

  // ---- V pass (Q-blocks only): pointwise tap, hi only; barrier-free ----
  if (!isK) {
    f32x4 av[4][8];
#pragma unroll
    for (int rt = 0; rt < 4; ++rt)
#pragma unroll
      for (int i = 0; i < 8; ++i)
#pragma unroll
        for (int r = 0; r < 4; ++r) av[rt][i][r] = 0.f;

#pragma unroll
    for (int g = 0; g < 4; ++g) {
#pragma unroll
      for (int s = 0; s < 2; ++s) {
        const int64_t vsrc = (int64_t)(o0 + (g * 2 + s) * 16) * 128 + wlane;
#pragma unroll
        for (int kk = 0; kk < 4; ++kk)
          dma16(Wvb + vsrc + kk * 32, wbuf + w * 4096 + s * 2048 + kk * 512);
      }
      wait_vm0();   // own DMA landed
#pragma unroll
      for (int kk = 0; kk < 4; ++kk) {
        f16x8 a[4];
#pragma unroll
        for (int rt = 0; rt < 4; ++rt)
          a[rt] = *(const f16x8*)&xbuf[(rt * 16 + lo + 4) * 264 + kk * 32 +
                                       quad * 8];
#pragma unroll
        for (int s = 0; s < 2; ++s) {
          const f16x8 bv8 = *(const f16x8*)&wbuf[w * 4096 + s * 2048 + kk * 512 +
                                                 quad * 128 + lo * 8];
#pragma unroll
          for (int rt = 0; rt < 4; ++rt)
            av[rt][g * 2 + s] = MFMA16(a[rt], bv8, av[rt][g * 2 + s]);
        }
      }
      wait_lgkm0();  // own ds_reads sampled before next DMA can land
    }
    __syncthreads();  // all waves done with wbuf before cross-wave staging
    // bias + stage v3T via LDS [kcl][t2l] (stride 264), two 256-col passes
#pragma unroll
    for (int pass = 0; pass < 2; ++pass) {
#pragma unroll
      for (int nt = 0; nt < 8; ++nt) {
        const int o = o0 + nt * 16 + lo;
        const float vbv = bv[o];
        const int kcl = (o >> 3) & 63, hh = o & 7;
#pragma unroll
        for (int rtl = 0; rtl < 2; ++rtl)
#pragma unroll
          for (int r = 0; r < 4; ++r) {
            const int t2l = (rtl * 16 + quad * 4 + r) * 8 + hh;
            lds[kcl * 264 + t2l] = (f16)(av[pass * 2 + rtl][nt][r] + vbv);
          }
      }
      __syncthreads();
#pragma unroll
      for (int p = 0; p < 8; ++p) {
        const int idx = p * 256 + tid;
        const int kcl = idx >> 5, t8 = (idx & 31) * 8;
        *(f16x8*)(v3T + ((int64_t)m * 128 + half * 64 + kcl) * 1024 + t2b +
                  pass * 256 + t8) = *(const f16x8*)&lds[kcl * 264 + t8];
      }
      __syncthreads();  // staging reads done before next pass / wbuf reuse
    }
  }

  // ---- Q or K main: (j, kk) outer, A-frags hoisted; 2 nt-groups each ----
  f32x4 aq[4][8];
#pragma unroll
  for (int rt = 0; rt < 4; ++rt)
#pragma unroll
    for (int i = 0; i < 8; ++i)
#pragma unroll
      for (int r = 0; r < 4; ++r) { aq[rt][i][r] = 0.f; }

  for (int j = 0; j < 5; ++j) {
    const bool z0 = (tloc == 0);
#pragma unroll
    for (int kk = 0; kk < 4; ++kk) {
      // hoisted A fragments for this (j,kk): independent of nt
      f16x8 ah[4], al[4];
#pragma unroll
      for (int rt = 0; rt < 4; ++rt) {
        ah[rt] = *(const f16x8*)&xbuf[(rt * 16 + lo + j) * 264 + kk * 32 +
                                      quad * 8];
        al[rt] = *(const f16x8*)&xbuf[(rt * 16 + lo + j) * 264 + 128 + kk * 32 +
                                      quad * 8];
      }
      if (z0 && (lo + j < 4)) {
#pragma unroll
        for (int e = 0; e < 8; ++e) { ah[0][e] = (f16)0; al[0][e] = (f16)0; }
      }
#pragma unroll
      for (int ntg = 0; ntg < 2; ++ntg) {
        const int64_t wsrc = (int64_t)j * 131072 + kk * 32 + wlane;
#pragma unroll
        for (int ntl = 0; ntl < 4; ++ntl) {
          const int nt = ntg * 4 + ntl;
          const int64_t o = wsrc + (int64_t)(o0 + nt * 16) * 128;
          dma16(Wh + o, wbuf + w * 4096 + ntl * 1024);
          dma16(Wl + o, wbuf + w * 4096 + ntl * 1024 + 512);
        }
        wait_vm4();   // ntl 0/1 (h+l) landed; ntl 2/3 still in flight
#pragma unroll
        for (int ntl = 0; ntl < 4; ++ntl) {
          if (ntl == 2) wait_vm0();   // ntl 2/3 landed
          const int nt = ntg * 4 + ntl;
          const f16x8 bh = *(const f16x8*)&wbuf[w * 4096 + ntl * 1024 +
                                                quad * 128 + lo * 8];
          const f16x8 bl = *(const f16x8*)&wbuf[w * 4096 + ntl * 1024 + 512 +
                                                quad * 128 + lo * 8];
#pragma unroll
          for (int rt = 0; rt < 4; ++rt) {
            aq[rt][nt] = MFMA16(ah[rt], bh, aq[rt][nt]);
            aq[rt][nt] = MFMA16(ah[rt], bl, aq[rt][nt]);
            aq[rt][nt] = MFMA16(al[rt], bh, aq[rt][nt]);
          }
        }
        wait_lgkm0();  // ds_reads sampled before next chunk's DMA lands
      }
    }
  }

  const float SC = 0.29730177875068026f;  // 128^-0.25
#pragma unroll
  for (int nt = 0; nt < 8; ++nt) {
    const int o = o0 + nt * 16 + lo;
    const float vb = bias[o];
#pragma unroll
    for (int rt = 0; rt < 4; ++rt)
#pragma unroll
      for (int r = 0; r < 4; ++r) aq[rt][nt][r] = (aq[rt][nt][r] + vb) * SC;
  }

  if (!isK) {
    STAGE_QK(q3h, 0, (f16)aq[rt][nt][r])
    STAGE_QK(q3h, 1, (f16)aq[rt][nt][r])
    STAGE_QK(q3l, 0, (f16)(aq[rt][nt][r] - (float)(f16)aq[rt][nt][r]))
    STAGE_QK(q3l, 1, (f16)(aq[rt][nt][r] - (float)(f16)aq[rt][nt][r]))
  } else {
    STAGE_QK(k3h, 0, (f16)aq[rt][nt][r])
    STAGE_QK(k3h, 1, (f16)aq[rt][nt][r])
    STAGE_QK(k3l, 0, (f16)(aq[rt][nt][r] - (float)(f16)aq[rt][nt][r]))
    STAGE_QK(k3l, 1, (f16)(aq[rt][nt][r] - (float)(f16)aq[rt][nt][r]))
  }
}

// ---------------- K234: DMA-streamed scores + top-64/softmax + PV ----------
// (R7 version: best measured, 239 us.) Coalescing-preserving bank-swizzle;
// radix early-exit; V pre-issued under radix, ping-pong pipelined;
// XCD m-swizzle; causal-truncated PV.
__global__ __launch_bounds__(512, 4) void k234_attn(
    const f16* __restrict__ q3h, const f16* __restrict__ q3l,
    const f16* __restrict__ k3h, const f16* __restrict__ k3l,
    const f16* __restrict__ v3T, f16* __restrict__ A) {
  __shared__ float Sb[16 * 516];   // 33,024 B: S fp32 half / P f16 full
  __shared__ f16 kbuf[16384];      // 32,768 B: 32 DMA slots x 512 f16
  const int tid = threadIdx.x;
  const int w = tid >> 6, lane = tid & 63;
  const int quad = lane >> 4, lo = lane & 15;
  const int qd = lane & 3, cit = lane >> 2;       // DMA lanes: [row][piece]
  const int qsw = qd ^ ((cit >> 1) & 3);          // bank-swizzled piece
  const int fro = (lo * 4 + (quad ^ ((lo >> 1) & 3))) * 8;  // fragment read
  // bijective XCD-locality remap of (m, r0): 4096 blocks = 8 xcd * 8 m * 64 r0
  const int hid = blockIdx.y * 64 + blockIdx.x;  // hardware linear id
  const int m = (hid & 7) * 8 + ((hid >> 3) >> 6);
  const int r0 = ((hid >> 3) & 63) * 16;

  // Q fragments (A-operand) for rows r0..r0+15, all K
  const int64_t qoff = ((int64_t)m * 1024 + r0 + lo) * 128;
  f16x8 qh[4], ql[4];
#pragma unroll
  for (int kk = 0; kk < 4; ++kk) {
    qh[kk] = ldfrag(q3h + qoff + kk * 32 + quad * 8);
    ql[kk] = ldfrag(q3l + qoff + kk * 32 + quad * 8);
  }

  unsigned key[2][16];
  unsigned kmn0 = 0xFFFFFFFFu, kmn1 = 0xFFFFFFFFu;

  // ---- phase 1: S = Q @ K^T, streamed; wave w owns col-tile w per chunk ---
#pragma unroll
  for (int half = 0; half < 2; ++half) {
    f32x4 acc[4];
#pragma unroll
    for (int i = 0; i < 4; ++i)
#pragma unroll
      for (int r = 0; r < 4; ++r) acc[i][r] = 0.f;

    for (int kp = 0; kp < 2; ++kp) {      // 64-K span (full 128B lines)
#pragma unroll
      for (int cc = 0; cc < 4; ++cc) {    // 128-col chunk
        const int c0 = half * 512 + cc * 128;
        const int64_t rowg = (int64_t)(m * 1024 + c0 + w * 16 + cit) * 128;
#pragma unroll
        for (int t = 0; t < 2; ++t) {
          const f16* srcb = t ? k3l : k3h;
#pragma unroll
          for (int kkh = 0; kkh < 2; ++kkh)
            dma16(srcb + rowg + (kp * 2 + kkh) * 32 + qsw * 8,
                  kbuf + (w * 4 + t * 2 + kkh) * 512);
        }
        wait_vm0();   // own DMA landed (slots are wave-private)
#pragma unroll
        for (int kkh = 0; kkh < 2; ++kkh) {
          const int kkg = kp * 2 + kkh;
          f16x8 bh = *(const f16x8*)(kbuf + (w * 4 + kkh) * 512 + fro);
          f16x8 bl = *(const f16x8*)(kbuf + (w * 4 + 2 + kkh) * 512 + fro);
          acc[cc] = MFMA16(qh[kkg], bh, acc[cc]);
          acc[cc] = MFMA16(qh[kkg], bl, acc[cc]);
          acc[cc] = MFMA16(ql[kkg], bh, acc[cc]);
        }
        wait_lgkm0();  // reads sampled before next chunk's DMA lands
      }
    }
    // write S half (cols half*512 .. +511)
#pragma unroll
    for (int cc = 0; cc < 4; ++cc)
#pragma unroll
      for (int r = 0; r < 4; ++r)
        Sb[(quad * 4 + r) * 516 + cc * 128 + w * 16 + lo] = acc[cc][r];
    __syncthreads();   // cross-wave: snapshot reads other waves' columns
    // snapshot keys: wave w owns rows 2w, 2w+1
#pragma unroll
    for (int rr = 0; rr < 2; ++rr) {
      const float4* rp = (const float4*)(Sb + (w * 2 + rr) * 516);
#pragma unroll
      for (int i2 = 0; i2 < 2; ++i2) {
        const float4 f4 = rp[i2 * 64 + lane];
        const float fe[4] = {f4.x, f4.y, f4.z, f4.w};
#pragma unroll
        for (int e = 0; e < 4; ++e) {
          const unsigned u = __builtin_bit_cast(unsigned, fe[e]);
          const unsigned k = (u & 0x80000000u) ? ~u : (u | 0x80000000u);
          key[rr][half * 8 + i2 * 4 + e] = k;
          if (rr == 0) kmn0 = min(kmn0, k); else kmn1 = min(kmn1, k);
        }
      }
    }
    __syncthreads();  // all key reads done before next half overwrites S
  }

  // ---- pre-issue V chunks 0/1 (slots free after phase-1 lgkm0); their ----
  // ---- latency hides under the radix phase below ------------------------
  const int64_t vrow = (int64_t)(m * 128 + w * 16 + cit) * 1024;
  const int nkb = (r0 >> 6) + 1;        // cols beyond r0+15 have P == 0
#define VISSUE(KB, PAIR)                                                 \
  {                                                                      \
    dma16(v3T + vrow + (KB) * 64 + qsw * 8,                              \
          kbuf + (w * 4 + (PAIR) * 2) * 512);                            \
    dma16(v3T + vrow + (KB) * 64 + 32 + qsw * 8,                         \
          kbuf + (w * 4 + (PAIR) * 2 + 1) * 512);                        \
  }
  VISSUE(0, 0)
  if (nkb > 1) VISSUE(1, 1)

  // ---- phase 2: exact fp32 top-64 + rowmin + causal + softmax -> P --------
  f16* P16 = (f16*)Sb;  // row stride 1032 f16 (= 516 f32)
  {
#pragma unroll
    for (int off = 32; off; off >>= 1) {
      kmn0 = min(kmn0, (unsigned)__shfl_xor((int)kmn0, off));
      kmn1 = min(kmn1, (unsigned)__shfl_xor((int)kmn1, off));
    }
    // radix-select with exact-count early exit: when count(>=c)==64 the
    // selected set {k>=c} IS the top-64 (identical to the full scan's set).
    unsigned th0 = 0u, th1 = 0u;
    bool d0 = false, d1 = false;
    for (int b = 31; b >= 0; --b) {
      if (!d0) {
        const unsigned c0 = th0 | (1u << b);
        int cnt0 = 0;
#pragma unroll
        for (int i = 0; i < 16; ++i)
          cnt0 += (int)__popcll(__ballot(key[0][i] >= c0));
        if (cnt0 >= 64) { th0 = c0; if (cnt0 == 64) d0 = true; }
      }
      if (!d1) {
        const unsigned c1 = th1 | (1u << b);
        int cnt1 = 0;
#pragma unroll
        for (int i = 0; i < 16; ++i)
          cnt1 += (int)__popcll(__ballot(key[1][i] >= c1));
        if (cnt1 >= 64) { th1 = c1; if (cnt1 == 64) d1 = true; }
      }
      if (d0 && d1) break;
    }

#pragma unroll
    for (int rr = 0; rr < 2; ++rr) {
      const unsigned kth = rr ? th1 : th0;
      const unsigned kmn = rr ? kmn1 : kmn0;
      const int row = w * 2 + rr, t2 = r0 + row;
      const unsigned umn = (kmn & 0x80000000u) ? (kmn ^ 0x80000000u) : ~kmn;
      const float mn = __builtin_bit_cast(float, umn);   // exact row min
      const unsigned ukv = (kth & 0x80000000u) ? (kth ^ 0x80000000u) : ~kth;
      const float kv = __builtin_bit_cast(float, ukv);   // selection threshold

      float ev[16];
      float sum = 0.f;
#pragma unroll
      for (int j = 0; j < 16; ++j) {
        const int s = (j >> 3) * 512 + ((j >> 2) & 1) * 256 + lane * 4 + (j & 3);
        const unsigned k = key[rr][j];
        const unsigned uu = (k & 0x80000000u) ? (k ^ 0x80000000u) : ~k;
        const float f = __builtin_bit_cast(float, uu);
        const float ww = (k >= kth) ? f : mn;
        const float x = (s <= t2) ? __expf(ww - kv) : 0.f;  // kv-stabilized
        ev[j] = x;
        sum += x;
      }
      for (int off = 32; off; off >>= 1) sum += __shfl_xor(sum, off);
      const float inv = 1.0f / sum;

      f16* prow = P16 + row * 1032;  // in place over this row's S
#pragma unroll
      for (int hh = 0; hh < 2; ++hh)
#pragma unroll
        for (int i2 = 0; i2 < 2; ++i2) {
          f16x4 pk;
#pragma unroll
          for (int e = 0; e < 4; ++e)
            pk[e] = (f16)(ev[hh * 8 + i2 * 4 + e] * inv);
          *(f16x4*)(prow + hh * 512 + i2 * 256 + lane * 4) = pk;
        }
    }
  }
  __syncthreads();  // P visible to all waves

  // ---- phase 3: A = P @ V, causal-truncated, ping-pong pipelined ---------
  {
    f32x4 oa0, oa1;
#pragma unroll
    for (int r = 0; r < 4; ++r) { oa0[r] = 0.f; oa1[r] = 0.f; }
    for (int kb = 0; kb < nkb; ++kb) {  // 64-K spans
      if (kb + 1 < nkb) wait_vm2();     // kb landed; kb+1 stays in flight
      else wait_vm0();
      const int pair = kb & 1;
      {
        const f16x8 vf0 = *(const f16x8*)(kbuf + (w * 4 + pair * 2) * 512 + fro);
        const f16x8 vf1 =
            *(const f16x8*)(kbuf + (w * 4 + pair * 2 + 1) * 512 + fro);
        const f16x8 af0 = *(const f16x8*)(P16 + lo * 1032 + kb * 64 + quad * 8);
        const f16x8 af1 =
            *(const f16x8*)(P16 + lo * 1032 + kb * 64 + 32 + quad * 8);
        oa0 = MFMA16(af0, vf0, oa0);
        oa1 = MFMA16(af1, vf1, oa1);
      }
      wait_lgkm0();                      // reads sampled before slot reuse
      if (kb + 2 < nkb) VISSUE(kb + 2, pair)
    }
#undef VISSUE
#pragma unroll
    for (int r = 0; r < 4; ++r)
      A[((int64_t)m * 1024 + r0 + quad * 4 + r) * 128 + w * 16 + lo] =
          (f16)(oa0[r] + oa1[r]);
  }
}

// ---------------- K5: gather + output projection + bias --------------------
__global__ __launch_bounds__(256) void k5_proj(
    const f16* __restrict__ A, const f16* __restrict__ Wub,
    const float* __restrict__ bu, float* __restrict__ out) {
  const int w = threadIdx.x >> 6, lane = threadIdx.x & 63;
  const int quad = lane >> 4, lo = lane & 15;
  const int rt = w & 1, ch = w >> 1;
  const int r0 = blockIdx.x * 32 + rt * 16;  // row in [0,8192) = b*1024 + t2
  const int r = r0 + lo;
  const int bI = r >> 10, t2 = r & 1023;

  f32x4 acc[4];
#pragma unroll
  for (int i = 0; i < 4; ++i)
#pragma unroll
    for (int rr = 0; rr < 4; ++rr) acc[i][rr] = 0.f;

#pragma unroll 2
  for (int kk = 0; kk < 32; ++kk) {
    const int o = kk * 32 + quad * 8;  // feature index 0..1023
    const int j = o >> 7, kc = o & 127;
    f16x8 a = ldfrag(A + (((int64_t)(bI * 8 + j) * 1024 + t2) * 128 + kc));
    f16x8 wb[4];
#pragma unroll
    for (int nt = 0; nt < 4; ++nt)
      wb[nt] = ldfrag(Wub + (int64_t)(ch * 64 + nt * 16 + lo) * 1024 + o);
#pragma unroll
    for (int nt = 0; nt < 4; ++nt) acc[nt] = MFMA16(a, wb[nt], acc[nt]);
  }
#pragma unroll
  for (int nt = 0; nt < 4; ++nt) {
    const int col = ch * 64 + nt * 16 + lo;
    const float bias = bu[col];
#pragma unroll
    for (int rr = 0; rr < 4; ++rr) {
      const int row = r0 + quad * 4 + rr;
      out[(int64_t)row * 128 + col] = acc[nt][rr] + bias;
    }
  }
}

// ---------------- launcher --------------------------------------------------
extern "C" void kernel_launch(void* const* d_in, const int* in_sizes, int n_in,
                              void* d_out, int out_size, void* d_ws, size_t ws_size,
                              hipStream_t stream) {
  const float* x  = (const float*)d_in[0];
  const float* Wq = (const float*)d_in[1];
  const float* bq = (const float*)d_in[2];
  const float* Wk = (const float*)d_in[3];
  const float* bk = (const float*)d_in[4];
  const float* Wv = (const float*)d_in[5];
  const float* bv = (const float*)d_in[6];
  const float* Wu = (const float*)d_in[7];
  const float* bu = (const float*)d_in[8];
  float* out = (float*)d_out;

  char* ws = (char*)d_ws;
  f16* xh  = (f16*)ws;  ws += 2097152;
  f16* xl  = (f16*)ws;  ws += 2097152;
  f16* Wqh = (f16*)ws;  ws += 1310720;
  f16* Wql = (f16*)ws;  ws += 1310720;
  f16* Wkh = (f16*)ws;  ws += 1310720;
  f16* Wkl = (f16*)ws;  ws += 1310720;
  f16* Wvb = (f16*)ws;  ws += 262144;
  f16* Wub = (f16*)ws;  ws += 262144;
  f16* q3h = (f16*)ws;  ws += 16777216;           // 64*1024*128 fp16
  f16* q3l = (f16*)ws;  ws += 16777216;
  f16* k3h = (f16*)ws;  ws += 16777216;
  f16* k3l = (f16*)ws;  ws += 16777216;
  f16* v3T = (f16*)ws;  ws += 16777216;
  f16* A   = (f16*)ws;  ws += 16777216;           // total ~105.5 MB

  // K0: repack (exactly 2621440 threads = 10240 * 256)
  k0_prep<<<10240, 256, 0, stream>>>(x, Wq, Wk, Wv, Wu,
                                     xh, xl, Wqh, Wql, Wkh, Wkl, Wvb, Wub);

  // K1: convs + scramble; 64 T-rows/block, A-frag-hoisted weight stream
  k1_conv<<<dim3(128, 2, 2), 256, 0, stream>>>(xh, xl, Wqh, Wql, Wkh, Wkl, Wvb,
                                               bq, bk, bv, q3h, q3l, k3h, k3l,
                                               v3T);

  // K234: R7 structure (swizzled conflict-free reads, V-under-radix)
  k234_attn<<<dim3(64, 64), 512, 0, stream>>>(q3h, q3l, k3h, k3l, v3T, A);

  // K5: projection (8192 rows / 32 per block)
  k5_proj<<<256, 256, 0, stream>>>(A, Wub, bu, out);

  (void)in_sizes; (void)n_in; (void)out_size; (void)ws_size;
}

// Round 10
// 408.187 us; speedup vs baseline: 1.0784x; 1.0087x over previous
//
#include <hip/hip_runtime.h>
#include <hip/hip_fp16.h>
#include <cstdint>

using f16 = _Float16;
typedef __attribute__((ext_vector_type(8))) _Float16 f16x8;
typedef __attribute__((ext_vector_type(4))) _Float16 f16x4;
typedef __attribute__((ext_vector_type(4))) float f32x4;

#define MFMA16(a, b, c) __builtin_amdgcn_mfma_f32_16x16x32_f16((a), (b), (c), 0, 0, 0)

__device__ __forceinline__ f16x8 ldfrag(const f16* p) { return *(const f16x8*)p; }

// async global->LDS DMA, 16 B per lane; lds dest = wave-uniform base + lane*16
__device__ __forceinline__ void dma16(const f16* g, f16* l) {
  __builtin_amdgcn_global_load_lds(
      (const __attribute__((address_space(1))) void*)g,
      (__attribute__((address_space(3))) void*)l, 16, 0, 0);
}
// explicit per-wave fences (do NOT rely on compiler LDS-DMA modeling)
__device__ __forceinline__ void wait_vm0() {
  asm volatile("s_waitcnt vmcnt(0)" ::: "memory");
}
__device__ __forceinline__ void wait_lgkm0() {
  asm volatile("s_waitcnt lgkmcnt(0)" ::: "memory");
}
__device__ __forceinline__ void wait_vm4() {
  asm volatile("s_waitcnt vmcnt(4)" ::: "memory");
}
__device__ __forceinline__ void wait_vm2() {
  asm volatile("s_waitcnt vmcnt(2)" ::: "memory");
}

// Problem constants: B=8, T=1024, K=128, H=8 -> M = B*H = 64 scrambled batches.
static const int64_t NX = 1048576;   // x elements: 8*1024*128
static const int64_t NW = 655360;    // Wq/Wk elements: 1024*128*5
static const int64_t NV = 131072;    // Wv / Wu elements: 1024*128

// ---------------- K0: split-convert/repack weights and x to fp16 hi/lo -----
__global__ __launch_bounds__(256) void k0_prep(
    const float* __restrict__ x, const float* __restrict__ Wq,
    const float* __restrict__ Wk, const float* __restrict__ Wv,
    const float* __restrict__ Wu,
    f16* __restrict__ xh, f16* __restrict__ xl,
    f16* __restrict__ Wqh, f16* __restrict__ Wql,
    f16* __restrict__ Wkh, f16* __restrict__ Wkl,
    f16* __restrict__ Wvb, f16* __restrict__ Wub) {
  int64_t i = (int64_t)blockIdx.x * 256 + threadIdx.x;  // grid sized exactly
  if (i < NX) {
    const float v = x[i];
    const f16 h = (f16)v;
    xh[i] = h; xl[i] = (f16)(v - (float)h);
  } else if (i < NX + NW) {
    int64_t d = i - NX;
    int j = (int)(d >> 17);
    int rem = (int)(d & 131071);
    int o = rem >> 7, c = rem & 127;
    const float v = Wq[(int64_t)(o * 128 + c) * 5 + j];   // layout [j][o][c]
    const f16 h = (f16)v;
    Wqh[d] = h; Wql[d] = (f16)(v - (float)h);
  } else if (i < NX + 2 * NW) {
    int64_t d = i - NX - NW;
    int j = (int)(d >> 17);
    int rem = (int)(d & 131071);
    int o = rem >> 7, c = rem & 127;
    const float v = Wk[(int64_t)(o * 128 + c) * 5 + j];
    const f16 h = (f16)v;
    Wkh[d] = h; Wkl[d] = (f16)(v - (float)h);
  } else if (i < NX + 2 * NW + NV) {
    int64_t d = i - NX - 2 * NW;
    Wvb[d] = (f16)Wv[d];                                // [o][c]
  } else {
    int64_t d = i - NX - 2 * NW - NV;
    Wub[d] = (f16)Wu[d];                                // [c][o]
  }
}

// ---------------- K1: causal convs, 64 T-rows/block ------------------------
// A-frags hoisted per (j,kk) (R9). Weight stream is now a CONTINUOUS
// half-chunk software pipeline across all 40 chunks: constant 8 DMAs
// (8 KB/wave) in flight, every wait vmcnt(4); full-latency exposure only at
// the single prologue (was 40 drains/wave). Consumption order unchanged ->
// bitwise-identical accumulation.
#define STAGE_QK(DST, PASS, VALEXPR)                                    \
  {                                                                     \
    __syncthreads();                                                    \
    _Pragma("unroll")                                                   \
    for (int nt = 0; nt < 8; ++nt) {                                    \
      const int o = o0 + nt * 16 + lo;                                  \
      const int kcl = (o >> 3) & 63, hh = o & 7;                        \
      _Pragma("unroll")                                                 \
      for (int rtl = 0; rtl < 2; ++rtl) {                               \
        const int rt = (PASS) * 2 + rtl;                                \
        _Pragma("unroll")                                               \
        for (int r = 0; r < 4; ++r) {                                   \
          const int t2l = (rtl * 16 + quad * 4 + r) * 8 + hh;           \
          lds[t2l * 72 + kcl] = (VALEXPR);                              \
        }                                                               \
      }                                                                 \
    }                                                                   \
    __syncthreads();                                                    \
    _Pragma("unroll")                                                   \
    for (int p = 0; p < 8; ++p) {                                       \
      const int idx = p * 256 + tid;                                    \
      const int a = idx >> 3, c8 = (idx & 7) * 8;                       \
      *(f16x8*)(DST + ((int64_t)m * 1024 + t2b + (PASS) * 256 + a) * 128 + \
                half * 64 + c8) = *(const f16x8*)&lds[a * 72 + c8];     \
    }                                                                   \
  }

__global__ __launch_bounds__(256) void k1_conv(
    const f16* __restrict__ xh, const f16* __restrict__ xl,
    const f16* __restrict__ Wqh, const f16* __restrict__ Wql,
    const f16* __restrict__ Wkh, const f16* __restrict__ Wkl,
    const f16* __restrict__ Wvb,
    const float* __restrict__ bq, const float* __restrict__ bk,
    const float* __restrict__ bv,
    f16* __restrict__ q3h, f16* __restrict__ q3l,
    f16* __restrict__ k3h, f16* __restrict__ k3l,
    f16* __restrict__ v3T) {
  __shared__ f16 shm[36384];      // 72.8 KB: [0,18432) wbuf/stage, rest xbuf
  f16* const wbuf = shm;
  f16* const xbuf = shm + 18432;  // 68 rows x 264 f16
  f16* const lds  = shm;          // staging alias
  const int tid = threadIdx.x;
  const int w = tid >> 6, lane = tid & 63;
  const int quad = lane >> 4, lo = lane & 15;
  const int r0 = blockIdx.x * 64;     // rows r0..r0+63 (same b, same m)
  const int bb = r0 >> 10;
  const int m  = r0 >> 7;
  const int t2b = (r0 & 127) * 8;     // 0 or 512
  const int tloc = r0 & 1023;
  const int half = blockIdx.y;        // which 512-channel half
  const int isK = blockIdx.z;         // 0 = Q (+V), 1 = K
  const int o0 = half * 512 + w * 128;

  const f16* Wh = isK ? Wkh : Wqh;
  const f16* Wl = isK ? Wkl : Wql;
  const float* bias = isK ? bk : bq;

  // ---- stage x rows [tloc-4, tloc+64) (clamped at batch start) ----
#pragma unroll
  for (int p = 0; p < 9; ++p) {
    const int u = p * 256 + tid;           // f16x8 unit
    if (u < 2176) {
      const int row = u >> 5, tz = (u >> 4) & 1, c8 = (u & 15) * 8;
      int lt = tloc - 4 + row;
      if (lt < 0) lt = 0;
      const f16* src = (tz ? xl : xh) + ((int64_t)(bb * 1024 + lt)) * 128 + c8;
      *(f16x8*)&xbuf[row * 264 + tz * 128 + c8] = *(const f16x8*)src;
    }
  }
  __syncthreads();

  // per-lane gather offset within a 16n x 128c fragment block
  const int64_t wlane = (int64_t)(lane & 15) * 128 + (lane >> 4) * 8;

  // ---- V pass (Q-blocks only): pointwise tap, hi only; barrier-free ----
  if (!isK) {
    f32x4 av[4][8];
#pragma unroll
    for (int rt = 0; rt < 4; ++rt)
#pragma unroll
      for (int i = 0; i < 8; ++i)
#pragma unroll
        for (int r = 0; r < 4; ++r) av[rt][i][r] = 0.f;

#pragma unroll
    for (int g = 0; g < 4; ++g) {
#pragma unroll
      for (int s = 0; s < 2; ++s) {
        const int64_t vsrc = (int64_t)(o0 + (g * 2 + s) * 16) * 128 + wlane;
#pragma unroll
        for (int kk = 0; kk < 4; ++kk)
          dma16(Wvb + vsrc + kk * 32, wbuf + w * 4096 + s * 2048 + kk * 512);
      }
      wait_vm0();   // own DMA landed
#pragma unroll
      for (int kk = 0; kk < 4; ++kk) {
        f16x8 a[4];
#pragma unroll
        for (int rt = 0; rt < 4; ++rt)
          a[rt] = *(const f16x8*)&xbuf[(rt * 16 + lo + 4) * 264 + kk * 32 +
                                       quad * 8];
#pragma unroll
        for (int s = 0; s < 2; ++s) {
          const f16x8 bv8 = *(const f16x8*)&wbuf[w * 4096 + s * 2048 + kk * 512 +
                                                 quad * 128 + lo * 8];
#pragma unroll
          for (int rt = 0; rt < 4; ++rt)
            av[rt][g * 2 + s] = MFMA16(a[rt], bv8, av[rt][g * 2 + s]);
        }
      }
      wait_lgkm0();  // own ds_reads sampled before next DMA can land
    }
    __syncthreads();  // all waves done with wbuf before cross-wave staging
    // bias + stage v3T via LDS [kcl][t2l] (stride 264), two 256-col passes
#pragma unroll
    for (int pass = 0; pass < 2; ++pass) {
#pragma unroll
      for (int nt = 0; nt < 8; ++nt) {
        const int o = o0 + nt * 16 + lo;
        const float vbv = bv[o];
        const int kcl = (o >> 3) & 63, hh = o & 7;
#pragma unroll
        for (int rtl = 0; rtl < 2; ++rtl)
#pragma unroll
          for (int r = 0; r < 4; ++r) {
            const int t2l = (rtl * 16 + quad * 4 + r) * 8 + hh;
            lds[kcl * 264 + t2l] = (f16)(av[pass * 2 + rtl][nt][r] + vbv);
          }
      }
      __syncthreads();
#pragma unroll
      for (int p = 0; p < 8; ++p) {
        const int idx = p * 256 + tid;
        const int kcl = idx >> 5, t8 = (idx & 31) * 8;
        *(f16x8*)(v3T + ((int64_t)m * 128 + half * 64 + kcl) * 1024 + t2b +
                  pass * 256 + t8) = *(const f16x8*)&lds[kcl * 264 + t8];
      }
      __syncthreads();  // staging reads done before next pass / wbuf reuse
    }
  }

  // ---- Q or K main: continuous half-chunk pipeline over 40 chunks --------
  f32x4 aq[4][8];
#pragma unroll
  for (int rt = 0; rt < 4; ++rt)
#pragma unroll
    for (int i = 0; i < 8; ++i)
#pragma unroll
      for (int r = 0; r < 4; ++r) { aq[rt][i][r] = 0.f; }

  const int64_t wbase = wlane + (int64_t)o0 * 128;
  // half H (0: ntl 0-1, 1: ntl 2-3) of chunk (J, KK, NTG); J may be runtime
#define ISSUE_HALF(J, KK, NTG, H)                                       \
  {                                                                     \
    _Pragma("unroll")                                                   \
    for (int ntl2 = 0; ntl2 < 2; ++ntl2) {                              \
      const int ntl_ = (H) * 2 + ntl2;                                  \
      const int64_t o_ = wbase + (int64_t)(J) * 131072 + (KK) * 32 +    \
                         (int64_t)(((NTG) * 4 + ntl_) * 16) * 128;      \
      dma16(Wh + o_, wbuf + w * 4096 + ntl_ * 1024);                    \
      dma16(Wl + o_, wbuf + w * 4096 + ntl_ * 1024 + 512);              \
    }                                                                   \
  }

  ISSUE_HALF(0, 0, 0, 0)
  ISSUE_HALF(0, 0, 0, 1)

  const bool z0 = (tloc == 0);
  for (int j = 0; j < 5; ++j) {
    f16x8 ah[4], al[4];
#pragma unroll
    for (int c = 0; c < 8; ++c) {
      const int kk = c >> 1, ntg = c & 1;
      if (ntg == 0) {
        // hoisted A fragments for this (j,kk): independent of nt
#pragma unroll
        for (int rt = 0; rt < 4; ++rt) {
          ah[rt] = *(const f16x8*)&xbuf[(rt * 16 + lo + j) * 264 + kk * 32 +
                                        quad * 8];
          al[rt] = *(const f16x8*)&xbuf[(rt * 16 + lo + j) * 264 + 128 +
                                        kk * 32 + quad * 8];
        }
        if (z0 && (lo + j < 4)) {
#pragma unroll
          for (int e = 0; e < 8; ++e) { ah[0][e] = (f16)0; al[0][e] = (f16)0; }
        }
      }
      // next chunk coordinates (pipeline crosses kk and j boundaries)
      const int nj = (c == 7) ? j + 1 : j;
      const int nkk = (c == 7) ? 0 : ((c + 1) >> 1);
      const int nntg = (c == 7) ? 0 : ((c + 1) & 1);
      const bool more = (c < 7) || (j < 4);

      wait_vm4();                 // half0(j,c) landed; 4+ stay in flight
#pragma unroll
      for (int ntl = 0; ntl < 2; ++ntl) {
        const int nt = ntg * 4 + ntl;
        const f16x8 bh = *(const f16x8*)&wbuf[w * 4096 + ntl * 1024 +
                                              quad * 128 + lo * 8];
        const f16x8 bl = *(const f16x8*)&wbuf[w * 4096 + ntl * 1024 + 512 +
                                              quad * 128 + lo * 8];
#pragma unroll
        for (int rt = 0; rt < 4; ++rt) {
          aq[rt][nt] = MFMA16(ah[rt], bh, aq[rt][nt]);
          aq[rt][nt] = MFMA16(ah[rt], bl, aq[rt][nt]);
          aq[rt][nt] = MFMA16(al[rt], bh, aq[rt][nt]);
        }
      }
      wait_lgkm0();               // half0 reads sampled before slot reuse
      if (more) ISSUE_HALF(nj, nkk, nntg, 0)

      if (c == 7) {               // last chunk of j: maybe nothing behind
        if (j == 4) wait_vm0(); else wait_vm4();
      } else {
        wait_vm4();               // half1(j,c) landed
      }
#pragma unroll
      for (int ntl = 2; ntl < 4; ++ntl) {
        const int nt = ntg * 4 + ntl;
        const f16x8 bh = *(const f16x8*)&wbuf[w * 4096 + ntl * 1024 +
                                              quad * 128 + lo * 8];
        const f16x8 bl = *(const f16x8*)&wbuf[w * 4096 + ntl * 1024 + 512 +
                                              quad * 128 + lo * 8];
#pragma unroll
        for (int rt = 0; rt < 4; ++rt) {
          aq[rt][nt] = MFMA16(ah[rt], bh, aq[rt][nt]);
          aq[rt][nt] = MFMA16(ah[rt], bl, aq[rt][nt]);
          aq[rt][nt] = MFMA16(al[rt], bh, aq[rt][nt]);
        }
      }
      wait_lgkm0();               // half1 reads sampled before slot reuse
      if (more) ISSUE_HALF(nj, nkk, nntg, 1)
    }
  }
#undef ISSUE_HALF

  const float SC = 0.29730177875068026f;  // 128^-0.25
#pragma unroll
  for (int nt = 0; nt < 8; ++nt) {
    const int o = o0 + nt * 16 + lo;
    const float vb = bias[o];
#pragma unroll
    for (int rt = 0; rt < 4; ++rt)
#pragma unroll
      for (int r = 0; r < 4; ++r) aq[rt][nt][r] = (aq[rt][nt][r] + vb) * SC;
  }

  if (!isK) {
    STAGE_QK(q3h, 0, (f16)aq[rt][nt][r])
    STAGE_QK(q3h, 1, (f16)aq[rt][nt][r])
    STAGE_QK(q3l, 0, (f16)(aq[rt][nt][r] - (float)(f16)aq[rt][nt][r]))
    STAGE_QK(q3l, 1, (f16)(aq[rt][nt][r] - (float)(f16)aq[rt][nt][r]))
  } else {
    STAGE_QK(k3h, 0, (f16)aq[rt][nt][r])
    STAGE_QK(k3h, 1, (f16)aq[rt][nt][r])
    STAGE_QK(k3l, 0, (f16)(aq[rt][nt][r] - (float)(f16)aq[rt][nt][r]))
    STAGE_QK(k3l, 1, (f16)(aq[rt][nt][r] - (float)(f16)aq[rt][nt][r]))
  }
}

// ---------------- K234: DMA-streamed scores + top-64/softmax + PV ----------
// (R7 version: best measured, 239 us.) Coalescing-preserving bank-swizzle;
// radix early-exit; V pre-issued under radix, ping-pong pipelined;
// XCD m-swizzle; causal-truncated PV.
__global__ __launch_bounds__(512, 4) void k234_attn(
    const f16* __restrict__ q3h, const f16* __restrict__ q3l,
    const f16* __restrict__ k3h, const f16* __restrict__ k3l,
    const f16* __restrict__ v3T, f16* __restrict__ A) {
  __shared__ float Sb[16 * 516];   // 33,024 B: S fp32 half / P f16 full
  __shared__ f16 kbuf[16384];      // 32,768 B: 32 DMA slots x 512 f16
  const int tid = threadIdx.x;
  const int w = tid >> 6, lane = tid & 63;
  const int quad = lane >> 4, lo = lane & 15;
  const int qd = lane & 3, cit = lane >> 2;       // DMA lanes: [row][piece]
  const int qsw = qd ^ ((cit >> 1) & 3);          // bank-swizzled piece
  const int fro = (lo * 4 + (quad ^ ((lo >> 1) & 3))) * 8;  // fragment read
  // bijective XCD-locality remap of (m, r0): 4096 blocks = 8 xcd * 8 m * 64 r0
  const int hid = blockIdx.y * 64 + blockIdx.x;  // hardware linear id
  const int m = (hid & 7) * 8 + ((hid >> 3) >> 6);
  const int r0 = ((hid >> 3) & 63) * 16;

  // Q fragments (A-operand) for rows r0..r0+15, all K
  const int64_t qoff = ((int64_t)m * 1024 + r0 + lo) * 128;
  f16x8 qh[4], ql[4];
#pragma unroll
  for (int kk = 0; kk < 4; ++kk) {
    qh[kk] = ldfrag(q3h + qoff + kk * 32 + quad * 8);
    ql[kk] = ldfrag(q3l + qoff + kk * 32 + quad * 8);
  }

  unsigned key[2][16];
  unsigned kmn0 = 0xFFFFFFFFu, kmn1 = 0xFFFFFFFFu;

  // ---- phase 1: S = Q @ K^T, streamed; wave w owns col-tile w per chunk ---
#pragma unroll
  for (int half = 0; half < 2; ++half) {
    f32x4 acc[4];
#pragma unroll
    for (int i = 0; i < 4; ++i)
#pragma unroll
      for (int r = 0; r < 4; ++r) acc[i][r] = 0.f;

    for (int kp = 0; kp < 2; ++kp) {      // 64-K span (full 128B lines)
#pragma unroll
      for (int cc = 0; cc < 4; ++cc) {    // 128-col chunk
        const int c0 = half * 512 + cc * 128;
        const int64_t rowg = (int64_t)(m * 1024 + c0 + w * 16 + cit) * 128;
#pragma unroll
        for (int t = 0; t < 2; ++t) {
          const f16* srcb = t ? k3l : k3h;
#pragma unroll
          for (int kkh = 0; kkh < 2; ++kkh)
            dma16(srcb + rowg + (kp * 2 + kkh) * 32 + qsw * 8,
                  kbuf + (w * 4 + t * 2 + kkh) * 512);
        }
        wait_vm0();   // own DMA landed (slots are wave-private)
#pragma unroll
        for (int kkh = 0; kkh < 2; ++kkh) {
          const int kkg = kp * 2 + kkh;
          f16x8 bh = *(const f16x8*)(kbuf + (w * 4 + kkh) * 512 + fro);
          f16x8 bl = *(const f16x8*)(kbuf + (w * 4 + 2 + kkh) * 512 + fro);
          acc[cc] = MFMA16(qh[kkg], bh, acc[cc]);
          acc[cc] = MFMA16(qh[kkg], bl, acc[cc]);
          acc[cc] = MFMA16(ql[kkg], bh, acc[cc]);
        }
        wait_lgkm0();  // reads sampled before next chunk's DMA lands
      }
    }
    // write S half (cols half*512 .. +511)
#pragma unroll
    for (int cc = 0; cc < 4; ++cc)
#pragma unroll
      for (int r = 0; r < 4; ++r)
        Sb[(quad * 4 + r) * 516 + cc * 128 + w * 16 + lo] = acc[cc][r];
    __syncthreads();   // cross-wave: snapshot reads other waves' columns
    // snapshot keys: wave w owns rows 2w, 2w+1
#pragma unroll
    for (int rr = 0; rr < 2; ++rr) {
      const float4* rp = (const float4*)(Sb + (w * 2 + rr) * 516);
#pragma unroll
      for (int i2 = 0; i2 < 2; ++i2) {
        const float4 f4 = rp[i2 * 64 + lane];
        const float fe[4] = {f4.x, f4.y, f4.z, f4.w};
#pragma unroll
        for (int e = 0; e < 4; ++e) {
          const unsigned u = __builtin_bit_cast(unsigned, fe[e]);
          const unsigned k = (u & 0x80000000u) ? ~u : (u | 0x80000000u);
          key[rr][half * 8 + i2 * 4 + e] = k;
          if (rr == 0) kmn0 = min(kmn0, k); else kmn1 = min(kmn1, k);
        }
      }
    }
    __syncthreads();  // all key reads done before next half overwrites S
  }

  // ---- pre-issue V chunks 0/1 (slots free after phase-1 lgkm0); their ----
  // ---- latency hides under the radix phase below ------------------------
  const int64_t vrow = (int64_t)(m * 128 + w * 16 + cit) * 1024;
  const int nkb = (r0 >> 6) + 1;        // cols beyond r0+15 have P == 0
#define VISSUE(KB, PAIR)                                                 \
  {                                                                      \
    dma16(v3T + vrow + (KB) * 64 + qsw * 8,                              \
          kbuf + (w * 4 + (PAIR) * 2) * 512);                            \
    dma16(v3T + vrow + (KB) * 64 + 32 + qsw * 8,                         \
          kbuf + (w * 4 + (PAIR) * 2 + 1) * 512);                        \
  }
  VISSUE(0, 0)
  if (nkb > 1) VISSUE(1, 1)

  // ---- phase 2: exact fp32 top-64 + rowmin + causal + softmax -> P --------
  f16* P16 = (f16*)Sb;  // row stride 1032 f16 (= 516 f32)
  {
#pragma unroll
    for (int off = 32; off; off >>= 1) {
      kmn0 = min(kmn0, (unsigned)__shfl_xor((int)kmn0, off));
      kmn1 = min(kmn1, (unsigned)__shfl_xor((int)kmn1, off));
    }
    // radix-select with exact-count early exit: when count(>=c)==64 the
    // selected set {k>=c} IS the top-64 (identical to the full scan's set).
    unsigned th0 = 0u, th1 = 0u;
    bool d0 = false, d1 = false;
    for (int b = 31; b >= 0; --b) {
      if (!d0) {
        const unsigned c0 = th0 | (1u << b);
        int cnt0 = 0;
#pragma unroll
        for (int i = 0; i < 16; ++i)
          cnt0 += (int)__popcll(__ballot(key[0][i] >= c0));
        if (cnt0 >= 64) { th0 = c0; if (cnt0 == 64) d0 = true; }
      }
      if (!d1) {
        const unsigned c1 = th1 | (1u << b);
        int cnt1 = 0;
#pragma unroll
        for (int i = 0; i < 16; ++i)
          cnt1 += (int)__popcll(__ballot(key[1][i] >= c1));
        if (cnt1 >= 64) { th1 = c1; if (cnt1 == 64) d1 = true; }
      }
      if (d0 && d1) break;
    }

#pragma unroll
    for (int rr = 0; rr < 2; ++rr) {
      const unsigned kth = rr ? th1 : th0;
      const unsigned kmn = rr ? kmn1 : kmn0;
      const int row = w * 2 + rr, t2 = r0 + row;
      const unsigned umn = (kmn & 0x80000000u) ? (kmn ^ 0x80000000u) : ~kmn;
      const float mn = __builtin_bit_cast(float, umn);   // exact row min
      const unsigned ukv = (kth & 0x80000000u) ? (kth ^ 0x80000000u) : ~kth;
      const float kv = __builtin_bit_cast(float, ukv);   // selection threshold

      float ev[16];
      float sum = 0.f;
#pragma unroll
      for (int j = 0; j < 16; ++j) {
        const int s = (j >> 3) * 512 + ((j >> 2) & 1) * 256 + lane * 4 + (j & 3);
        const unsigned k = key[rr][j];
        const unsigned uu = (k & 0x80000000u) ? (k ^ 0x80000000u) : ~k;
        const float f = __builtin_bit_cast(float, uu);
        const float ww = (k >= kth) ? f : mn;
        const float x = (s <= t2) ? __expf(ww - kv) : 0.f;  // kv-stabilized
        ev[j] = x;
        sum += x;
      }
      for (int off = 32; off; off >>= 1) sum += __shfl_xor(sum, off);
      const float inv = 1.0f / sum;

      f16* prow = P16 + row * 1032;  // in place over this row's S
#pragma unroll
      for (int hh = 0; hh < 2; ++hh)
#pragma unroll
        for (int i2 = 0; i2 < 2; ++i2) {
          f16x4 pk;
#pragma unroll
          for (int e = 0; e < 4; ++e)
            pk[e] = (f16)(ev[hh * 8 + i2 * 4 + e] * inv);
          *(f16x4*)(prow + hh * 512 + i2 * 256 + lane * 4) = pk;
        }
    }
  }
  __syncthreads();  // P visible to all waves

  // ---- phase 3: A = P @ V, causal-truncated, ping-pong pipelined ---------
  {
    f32x4 oa0, oa1;
#pragma unroll
    for (int r = 0; r < 4; ++r) { oa0[r] = 0.f; oa1[r] = 0.f; }
    for (int kb = 0; kb < nkb; ++kb) {  // 64-K spans
      if (kb + 1 < nkb) wait_vm2();     // kb landed; kb+1 stays in flight
      else wait_vm0();
      const int pair = kb & 1;
      {
        const f16x8 vf0 = *(const f16x8*)(kbuf + (w * 4 + pair * 2) * 512 + fro);
        const f16x8 vf1 =
            *(const f16x8*)(kbuf + (w * 4 + pair * 2 + 1) * 512 + fro);
        const f16x8 af0 = *(const f16x8*)(P16 + lo * 1032 + kb * 64 + quad * 8);
        const f16x8 af1 =
            *(const f16x8*)(P16 + lo * 1032 + kb * 64 + 32 + quad * 8);
        oa0 = MFMA16(af0, vf0, oa0);
        oa1 = MFMA16(af1, vf1, oa1);
      }
      wait_lgkm0();                      // reads sampled before slot reuse
      if (kb + 2 < nkb) VISSUE(kb + 2, pair)
    }
#undef VISSUE
#pragma unroll
    for (int r = 0; r < 4; ++r)
      A[((int64_t)m * 1024 + r0 + quad * 4 + r) * 128 + w * 16 + lo] =
          (f16)(oa0[r] + oa1[r]);
  }
}

// ---------------- K5: gather + output projection + bias --------------------
__global__ __launch_bounds__(256) void k5_proj(
    const f16* __restrict__ A, const f16* __restrict__ Wub,
    const float* __restrict__ bu, float* __restrict__ out) {
  const int w = threadIdx.x >> 6, lane = threadIdx.x & 63;
  const int quad = lane >> 4, lo = lane & 15;
  const int rt = w & 1, ch = w >> 1;
  const int r0 = blockIdx.x * 32 + rt * 16;  // row in [0,8192) = b*1024 + t2
  const int r = r0 + lo;
  const int bI = r >> 10, t2 = r & 1023;

  f32x4 acc[4];
#pragma unroll
  for (int i = 0; i < 4; ++i)
#pragma unroll
    for (int rr = 0; rr < 4; ++rr) acc[i][rr] = 0.f;

#pragma unroll 2
  for (int kk = 0; kk < 32; ++kk) {
    const int o = kk * 32 + quad * 8;  // feature index 0..1023
    const int j = o >> 7, kc = o & 127;
    f16x8 a = ldfrag(A + (((int64_t)(bI * 8 + j) * 1024 + t2) * 128 + kc));
    f16x8 wb[4];
#pragma unroll
    for (int nt = 0; nt < 4; ++nt)
      wb[nt] = ldfrag(Wub + (int64_t)(ch * 64 + nt * 16 + lo) * 1024 + o);
#pragma unroll
    for (int nt = 0; nt < 4; ++nt) acc[nt] = MFMA16(a, wb[nt], acc[nt]);
  }
#pragma unroll
  for (int nt = 0; nt < 4; ++nt) {
    const int col = ch * 64 + nt * 16 + lo;
    const float bias = bu[col];
#pragma unroll
    for (int rr = 0; rr < 4; ++rr) {
      const int row = r0 + quad * 4 + rr;
      out[(int64_t)row * 128 + col] = acc[nt][rr] + bias;
    }
  }
}

// ---------------- launcher --------------------------------------------------
extern "C" void kernel_launch(void* const* d_in, const int* in_sizes, int n_in,
                              void* d_out, int out_size, void* d_ws, size_t ws_size,
                              hipStream_t stream) {
  const float* x  = (const float*)d_in[0];
  const float* Wq = (const float*)d_in[1];
  const float* bq = (const float*)d_in[2];
  const float* Wk = (const float*)d_in[3];
  const float* bk = (const float*)d_in[4];
  const float* Wv = (const float*)d_in[5];
  const float* bv = (const float*)d_in[6];
  const float* Wu = (const float*)d_in[7];
  const float* bu = (const float*)d_in[8];
  float* out = (float*)d_out;

  char* ws = (char*)d_ws;
  f16* xh  = (f16*)ws;  ws += 2097152;
  f16* xl  = (f16*)ws;  ws += 2097152;
  f16* Wqh = (f16*)ws;  ws += 1310720;
  f16* Wql = (f16*)ws;  ws += 1310720;
  f16* Wkh = (f16*)ws;  ws += 1310720;
  f16* Wkl = (f16*)ws;  ws += 1310720;
  f16* Wvb = (f16*)ws;  ws += 262144;
  f16* Wub = (f16*)ws;  ws += 262144;
  f16* q3h = (f16*)ws;  ws += 16777216;           // 64*1024*128 fp16
  f16* q3l = (f16*)ws;  ws += 16777216;
  f16* k3h = (f16*)ws;  ws += 16777216;
  f16* k3l = (f16*)ws;  ws += 16777216;
  f16* v3T = (f16*)ws;  ws += 16777216;
  f16* A   = (f16*)ws;  ws += 16777216;           // total ~105.5 MB

  // K0: repack (exactly 2621440 threads = 10240 * 256)
  k0_prep<<<10240, 256, 0, stream>>>(x, Wq, Wk, Wv, Wu,
                                     xh, xl, Wqh, Wql, Wkh, Wkl, Wvb, Wub);

  // K1: convs + scramble; 64 T-rows/block, pipelined weight stream
  k1_conv<<<dim3(128, 2, 2), 256, 0, stream>>>(xh, xl, Wqh, Wql, Wkh, Wkl, Wvb,
                                               bq, bk, bv, q3h, q3l, k3h, k3l,
                                               v3T);

  // K234: R7 structure (swizzled conflict-free reads, V-under-radix)
  k234_attn<<<dim3(64, 64), 512, 0, stream>>>(q3h, q3l, k3h, k3l, v3T, A);

  // K5: projection (8192 rows / 32 per block)
  k5_proj<<<256, 256, 0, stream>>>(A, Wub, bu, out);

  (void)in_sizes; (void)n_in; (void)out_size; (void)ws_size;
}